// Round 1
// baseline (146.409 us; speedup 1.0000x reference)
//
#include <hip/hip_runtime.h>

// Problem constants (fixed by the reference)
#define BATCH 128
#define C 64
#define L 4096
#define K 31
#define PADH 15          // (K-1)/2

// Tiling
#define NTHREADS 256
#define R 4                       // outputs per thread
#define TILE_L (NTHREADS * R)     // 1024
#define PAD 16                    // halo (need 15; 16 keeps float4 alignment)
#define TILE_W (TILE_L + 2 * PAD) // 1056 floats staged per channel
#define CH 8                      // channels staged per group

// out[b,o,l] = S[b,l] for all o, where
//   S[b,l] = sum_i sum_k w[i,k] * x[b,i,l+15-k]  (x zero outside [0,L))
// w = kernel[0,:,:] (broadcast makes all o-slices identical).
__global__ __launch_bounds__(NTHREADS, 2)
void revconv_kernel(const float* __restrict__ x,
                    const float* __restrict__ w,
                    float* __restrict__ out) {
    __shared__ __align__(16) float xlds[CH][TILE_W];

    const int tid = threadIdx.x;
    const int tile = blockIdx.x;   // 0..3
    const int b = blockIdx.y;      // 0..127
    const int lstart = tile * TILE_L;

    float acc[R];
#pragma unroll
    for (int r = 0; r < R; ++r) acc[r] = 0.f;

    for (int g = 0; g < C / CH; ++g) {
        __syncthreads();   // protect previous group's reads before overwrite
        // ---- stage CH channels into LDS (coalesced float4, zero-padded) ----
#pragma unroll
        for (int ch = 0; ch < CH; ++ch) {
            const float* xp = x + ((long)b * C + (g * CH + ch)) * L;
            for (int p4 = tid; p4 < TILE_W / 4; p4 += NTHREADS) {
                const int g0 = lstart - PAD + p4 * 4;
                float4 v;
                if (g0 >= 0 && g0 + 3 < L) {
                    v = *reinterpret_cast<const float4*>(xp + g0);
                } else {
                    v.x = (g0 + 0 >= 0 && g0 + 0 < L) ? xp[g0 + 0] : 0.f;
                    v.y = (g0 + 1 >= 0 && g0 + 1 < L) ? xp[g0 + 1] : 0.f;
                    v.z = (g0 + 2 >= 0 && g0 + 2 < L) ? xp[g0 + 2] : 0.f;
                    v.w = (g0 + 3 >= 0 && g0 + 3 < L) ? xp[g0 + 3] : 0.f;
                }
                *reinterpret_cast<float4*>(&xlds[ch][p4 * 4]) = v;
            }
        }
        __syncthreads();

        // ---- compute: register window + unrolled taps ----
#pragma unroll
        for (int ch = 0; ch < CH; ++ch) {
            const int i = g * CH + ch;
            // window covers lds indices [tid*R .. tid*R+35]
            float win[R + 2 * PAD];   // 36 floats
            float4* w4 = reinterpret_cast<float4*>(win);
#pragma unroll
            for (int j = 0; j < (R + 2 * PAD) / 4; ++j)
                w4[j] = *reinterpret_cast<const float4*>(&xlds[ch][tid * R + j * 4]);

            const float* wp = w + i * K;   // uniform address -> s_load path
#pragma unroll
            for (int k = 0; k < K; ++k) {
                const float wk = wp[k];
#pragma unroll
                for (int r = 0; r < R; ++r) {
                    // lds index = tid*R + r + 31 - k, window-local j = r + 31 - k
                    acc[r] += wk * win[r + 31 - k];
                }
            }
        }
    }

    // ---- broadcast-store S to all 64 output channels ----
    const int l0 = lstart + tid * R;
    const float4 v = make_float4(acc[0], acc[1], acc[2], acc[3]);
    float* op = out + (long)b * C * L + l0;
#pragma unroll 8
    for (int o = 0; o < C; ++o) {
        *reinterpret_cast<float4*>(op + (long)o * L) = v;
    }
}

extern "C" void kernel_launch(void* const* d_in, const int* in_sizes, int n_in,
                              void* d_out, int out_size, void* d_ws, size_t ws_size,
                              hipStream_t stream) {
    const float* x = (const float*)d_in[0];   // [B, C, L] fp32
    const float* w = (const float*)d_in[1];   // [C, C, K] fp32; use o=0 slice
    float* out = (float*)d_out;               // [B, C, L] fp32

    dim3 grid(L / TILE_L, BATCH);
    dim3 block(NTHREADS);
    revconv_kernel<<<grid, block, 0, stream>>>(x, w, out);
}

// Round 3
// 121.086 us; speedup vs baseline: 1.2091x; 1.2091x over previous
//
#include <hip/hip_runtime.h>

// Problem constants (fixed by the reference)
#define BATCH 128
#define C 64
#define L 4096
#define K 31

// Tiling
#define NTHREADS 256
#define R 4                       // outputs per thread
#define TILE_L (NTHREADS * R)     // 1024 outputs per block
#define WIN 36                    // aligned register window [l0-16, l0+20)

typedef float floatx4 __attribute__((ext_vector_type(4)));  // clang vector: OK for nontemporal builtins

// out[b,o,l] = S[b,l] for all o (kernel is broadcast over o), where
//   S[b,l] = sum_i sum_k w[i,k] * x[b,i,l+15-k]   (x zero outside [0,L))
// w = kernel[0,:,:].
//
// No LDS, no barriers: each thread computes 4 consecutive outputs, loading
// its 36-float window per channel directly from global (9x float4; the 9x
// request amplification across overlapping windows is absorbed by L1 — the
// per-block per-channel working set is 4.2 KB).
__global__ __launch_bounds__(NTHREADS)
void revconv_kernel(const float* __restrict__ x,
                    const float* __restrict__ w,
                    float* __restrict__ out) {
    const int tid = threadIdx.x;
    const int tile = blockIdx.x;   // 0..3
    const int b = blockIdx.y;      // 0..127
    const int l0 = tile * TILE_L + tid * R;   // first output index of thread

    float acc[R] = {0.f, 0.f, 0.f, 0.f};

    const float* xb = x + (long)b * C * L;
    const bool interior = (l0 >= 16) && (l0 + 20 <= L);

    if (interior) {
        const float* xw = xb + (l0 - 16);   // 16B-aligned (l0 % 4 == 0)
#pragma unroll 2
        for (int i = 0; i < C; ++i) {
            float win[WIN];
            const floatx4* p = reinterpret_cast<const floatx4*>(xw + (long)i * L);
#pragma unroll
            for (int j = 0; j < WIN / 4; ++j)
                reinterpret_cast<floatx4*>(win)[j] = p[j];

            const float* wp = w + i * K;   // wave-uniform -> scalar loads
#pragma unroll
            for (int k = 0; k < K; ++k) {
                const float wk = wp[k];
#pragma unroll
                for (int r = 0; r < R; ++r)
                    acc[r] += wk * win[r + 31 - k];   // win[j] = x[l0-16+j]
            }
        }
    } else {
        // Edge threads (8 threads total per [b] row): guarded scalar loads.
        for (int i = 0; i < C; ++i) {
            const float* xi = xb + (long)i * L;
            float win[WIN];
#pragma unroll
            for (int j = 0; j < WIN; ++j) {
                const int g = l0 - 16 + j;
                win[j] = (g >= 0 && g < L) ? xi[g] : 0.f;
            }
            const float* wp = w + i * K;
#pragma unroll
            for (int k = 0; k < K; ++k) {
                const float wk = wp[k];
#pragma unroll
                for (int r = 0; r < R; ++r)
                    acc[r] += wk * win[r + 31 - k];
            }
        }
    }

    // Broadcast-store S to all 64 output channels (streaming, nontemporal).
    float* op = out + (long)b * C * L + l0;
    floatx4 v;
    v.x = acc[0]; v.y = acc[1]; v.z = acc[2]; v.w = acc[3];
#pragma unroll
    for (int o = 0; o < C; ++o)
        __builtin_nontemporal_store(v, reinterpret_cast<floatx4*>(op + (long)o * L));
}

extern "C" void kernel_launch(void* const* d_in, const int* in_sizes, int n_in,
                              void* d_out, int out_size, void* d_ws, size_t ws_size,
                              hipStream_t stream) {
    const float* x = (const float*)d_in[0];   // [B, C, L] fp32
    const float* w = (const float*)d_in[1];   // [C, C, K] fp32; o=0 slice used
    float* out = (float*)d_out;               // [B, C, L] fp32

    dim3 grid(L / TILE_L, BATCH);
    dim3 block(NTHREADS);
    revconv_kernel<<<grid, block, 0, stream>>>(x, w, out);
}